// Round 15
// baseline (165.588 us; speedup 1.0000x reference)
//
#include <hip/hip_runtime.h>
#include <hip/hip_bf16.h>
#include <stdint.h>

// B,C,H,W = 2,64,96,96. Inputs fp32, output fp32.
// proj3: QKV 1x1 convs -> bf16 q(*log2e), k, V key-PERMUTED channel-major.
// attn9: zero-LDS-loop flash attention, 64q/wave, ping-pong K+V prefetch
//        with NAMED SCALAR fragments (r14's lambda/pointer form spilled to
//        scratch: WRITE_SIZE 19->166MB), Schraudolph bf16 P, ones-row-MFMA
//        denominator, balanced padded-LDS epilogue.
// combine: sum G key-split partials, normalize, + gamma*attn + x.
#define BB 2
#define CC 64
#define PP 9216
#define QTILES 144               // PP/64
#define LOG2E 1.4426950408889634f
// Schraudolph magic for bf16 2^E bits: E*128 + (127 - 0.05730496)*128
#define SCH_C 16248.664965f

typedef unsigned short ushort;
typedef __attribute__((ext_vector_type(8))) short short8;
typedef __attribute__((ext_vector_type(4))) float floatx4;
typedef __attribute__((ext_vector_type(4))) int intx4;

__device__ __forceinline__ ushort f2bf(float f) {
    unsigned int u = __float_as_uint(f);
    u = (u + 0x7fffu + ((u >> 16) & 1u)) >> 16;   // RNE
    return (ushort)u;
}

// 2^e0, 2^e1 as packed bf16 pair via Schraudolph (arg always > 0 -> trunc=floor)
__device__ __forceinline__ unsigned int exp2_pk_bf16(float e0, float e1) {
    const int i0 = (int)fmaf(e0, 128.f, SCH_C);
    const int i1 = (int)fmaf(e1, 128.f, SCH_C);
    return (unsigned int)i0 | ((unsigned int)i1 << 16);
}

// ---------------------------------------------------------------------------
// Kernel 1: QKV projection. 576 blocks x 256 (4 waves; wave = 64 px x 10 rows;
// 2 blocks per 64-px tile, each covering 40 of the 80 output rows).
// Rows 0-7: q (scaled by LOG2E), 8-15: k, 16-79: v.
// V keys permuted within 32-groups: slot = ((k>>2)&3)*8 + ((k>>4)&1)*4 + (k&3)
// so PV's B-operand slot k'=quad*8+j matches QK's D[key][q] output rows.
// ---------------------------------------------------------------------------
__global__ __launch_bounds__(256)
void proj3(const float* __restrict__ x,
           const float* __restrict__ Wq, const float* __restrict__ bq,
           const float* __restrict__ Wk, const float* __restrict__ bk,
           const float* __restrict__ Wv, const float* __restrict__ bv,
           ushort* __restrict__ qbuf, ushort* __restrict__ kbuf,
           ushort* __restrict__ vfw)
{
    const int tid = threadIdx.x;
    const int px  = tid & 63;
    const int og  = __builtin_amdgcn_readfirstlane(tid >> 6);  // 0..3, wave-uniform
    const int blk = blockIdx.x;
    const int b     = blk / (2 * QTILES);
    const int rem   = blk % (2 * QTILES);
    const int ptile = rem >> 1;
    const int rhalf = rem & 1;
    const int p     = ptile * 64 + px;
    const int r0    = rhalf * 40 + og * 10;      // first of this thread's 10 rows

    const float* wr[10];
#pragma unroll
    for (int r = 0; r < 10; ++r) {
        const int row = r0 + r;
        wr[r] = (row < 8) ? (Wq + row * 64)
              : (row < 16) ? (Wk + (row - 8) * 64)
              : (Wv + (row - 16) * 64);
    }

    float xv[64];
#pragma unroll
    for (int c = 0; c < 64; ++c)
        xv[c] = x[((size_t)b * 64 + c) * PP + p];

    float acc[10];
#pragma unroll
    for (int r = 0; r < 10; ++r) acc[r] = 0.f;
#pragma unroll
    for (int c = 0; c < 64; ++c) {
#pragma unroll
        for (int r = 0; r < 10; ++r)
            acc[r] = fmaf(wr[r][c], xv[c], acc[r]);
    }

#pragma unroll
    for (int r = 0; r < 10; ++r) {
        const int row = r0 + r;
        if (row < 8) {
            const float v = (acc[r] + bq[row]) * LOG2E;
            qbuf[((size_t)b * PP + p) * 8 + row] = f2bf(v);
        } else if (row < 16) {
            const float v = acc[r] + bk[row - 8];
            kbuf[((size_t)b * PP + p) * 8 + (row - 8)] = f2bf(v);
        } else {
            const int co = row - 16;
            const float v = acc[r] + bv[co];
            const int pl = p & 31;     // slot permutation within 32-group
            const int ps = (p & ~31) | ((((pl >> 2) & 3) << 3) | (((pl >> 4) & 1) << 2) | (pl & 3));
            vfw[((size_t)b * 64 + co) * PP + ps] = f2bf(v);
        }
    }
}

// One tile's compute: QK (A=K, B=Q) -> Schraudolph bf16 P -> lsum MFMA -> PV.
// Expanded via macro over NAMED variables only — nothing can be demoted to
// scratch (r14 lesson: pointer-to-array args spill).
#define COMPUTE_TILE(K0, K1, V0, V1, V2, V3)                                   \
    _Pragma("unroll")                                                          \
    for (int qh = 0; qh < 4; ++qh) {                                           \
        const floatx4 E0 = __builtin_amdgcn_mfma_f32_16x16x32_bf16(            \
            K0, qfragB[qh], (floatx4){0.f, 0.f, 0.f, 0.f}, 0, 0, 0);           \
        const floatx4 E1 = __builtin_amdgcn_mfma_f32_16x16x32_bf16(            \
            K1, qfragB[qh], (floatx4){0.f, 0.f, 0.f, 0.f}, 0, 0, 0);           \
        intx4 pi;                                                              \
        pi.x = (int)exp2_pk_bf16(E0[0], E0[1]);                                \
        pi.y = (int)exp2_pk_bf16(E0[2], E0[3]);                                \
        pi.z = (int)exp2_pk_bf16(E1[0], E1[1]);                                \
        pi.w = (int)exp2_pk_bf16(E1[2], E1[3]);                                \
        const short8 pf = __builtin_bit_cast(short8, pi);                      \
        accLh[qh] = __builtin_amdgcn_mfma_f32_16x16x32_bf16(                   \
            vones, pf, accLh[qh], 0, 0, 0);                                    \
        acc[qh][0] = __builtin_amdgcn_mfma_f32_16x16x32_bf16(                  \
            V0, pf, acc[qh][0], 0, 0, 0);                                      \
        acc[qh][1] = __builtin_amdgcn_mfma_f32_16x16x32_bf16(                  \
            V1, pf, acc[qh][1], 0, 0, 0);                                      \
        acc[qh][2] = __builtin_amdgcn_mfma_f32_16x16x32_bf16(                  \
            V2, pf, acc[qh][2], 0, 0, 0);                                      \
        acc[qh][3] = __builtin_amdgcn_mfma_f32_16x16x32_bf16(                  \
            V3, pf, acc[qh][3], 0, 0, 0);                                      \
    }

// ---------------------------------------------------------------------------
// Kernel 2: zero-LDS-loop MFMA flash attention, 64q/wave, ping-pong K+V
// prefetch (named scalars). Grid = G*BB*QTILES blocks of 128 (2 waves; wave
// = 64 q x 32 keys of each 64-key tile). K quads 1-3 load garbage (Q k-slots
// >=8 zeroed -> contributes exactly 0). V key-permuted to PV slot order.
// Balanced epilogue: each wave exports its other channel-half via padded LDS.
// ---------------------------------------------------------------------------
__global__ __launch_bounds__(128, 3)
void attn9(const ushort* __restrict__ qbuf, const ushort* __restrict__ kbuf,
           const ushort* __restrict__ vfw,
           ushort* __restrict__ accp, float* __restrict__ lsump,
           int keysPerG, int numTiles)
{
    __shared__ __align__(16) float sx[2][32][66];  // padded: quad-stride 264 % 32 = 8
    __shared__ float slsum[64];

    const int tid  = threadIdx.x;
    const int lane = tid & 63;
    const int wid  = tid >> 6;
    const int col  = lane & 15;
    const int quad = lane >> 4;

    const int qt = blockIdx.x % QTILES;
    const int gb = blockIdx.x / QTILES;
    const int b  = gb % BB;
    const int g  = gb / BB;
    const int q0 = qt * 64;

    const short8 zf = {0, 0, 0, 0, 0, 0, 0, 0};
    const short vone = (short)0x3F80;                 // bf16 1.0
    const short8 vones = {vone, vone, vone, vone, vone, vone, vone, vone};

    // Q fragments (B-operand: B[k=d=quad*8+j][n=q=col]); only quad 0 real.
    short8 qfragB[4];
#pragma unroll
    for (int qh = 0; qh < 4; ++qh)
        qfragB[qh] = (quad == 0)
            ? *(const short8*)(qbuf + ((size_t)b * PP + q0 + qh * 16 + col) * 8)
            : zf;

    floatx4 acc[4][4];
#pragma unroll
    for (int qh = 0; qh < 4; ++qh)
#pragma unroll
        for (int cb = 0; cb < 4; ++cb) acc[qh][cb] = (floatx4){0.f, 0.f, 0.f, 0.f};
    floatx4 accLh[4];
#pragma unroll
    for (int qh = 0; qh < 4; ++qh) accLh[qh] = (floatx4){0.f, 0.f, 0.f, 0.f};

    const ushort* kB = kbuf + (size_t)b * PP * 8;
    const ushort* vB = vfw + (size_t)b * 64 * PP;
    const int kwbase = g * keysPerG + wid * 32;

    // ---- prologue: tile 0 into A-buffers (all named scalars) ----
    short8 kfa0 = *(const short8*)(kB + (size_t)(kwbase + col) * 8 + quad * 8);
    short8 kfa1 = *(const short8*)(kB + (size_t)(kwbase + 16 + col) * 8 + quad * 8);
    short8 vfa0 = *(const short8*)(vB + ((size_t)(0 * 16 + col)) * PP + kwbase + quad * 8);
    short8 vfa1 = *(const short8*)(vB + ((size_t)(1 * 16 + col)) * PP + kwbase + quad * 8);
    short8 vfa2 = *(const short8*)(vB + ((size_t)(2 * 16 + col)) * PP + kwbase + quad * 8);
    short8 vfa3 = *(const short8*)(vB + ((size_t)(3 * 16 + col)) * PP + kwbase + quad * 8);

    // numTiles is even for every G in the ladder (18/24/36/72)
    for (int t = 0; t < numTiles; t += 2) {
        // -- half A: prefetch tile t+1 into B-buffers, compute tile t --
        const int kw1 = kwbase + (t + 1) * 64;
        const short8 kfb0 = *(const short8*)(kB + (size_t)(kw1 + col) * 8 + quad * 8);
        const short8 kfb1 = *(const short8*)(kB + (size_t)(kw1 + 16 + col) * 8 + quad * 8);
        const short8 vfb0 = *(const short8*)(vB + ((size_t)(0 * 16 + col)) * PP + kw1 + quad * 8);
        const short8 vfb1 = *(const short8*)(vB + ((size_t)(1 * 16 + col)) * PP + kw1 + quad * 8);
        const short8 vfb2 = *(const short8*)(vB + ((size_t)(2 * 16 + col)) * PP + kw1 + quad * 8);
        const short8 vfb3 = *(const short8*)(vB + ((size_t)(3 * 16 + col)) * PP + kw1 + quad * 8);

        COMPUTE_TILE(kfa0, kfa1, vfa0, vfa1, vfa2, vfa3)

        // -- half B: prefetch tile t+2 into A-buffers, compute tile t+1 --
        const int kw2 = (t + 2 < numTiles) ? (kwbase + (t + 2) * 64) : kw1;
        kfa0 = *(const short8*)(kB + (size_t)(kw2 + col) * 8 + quad * 8);
        kfa1 = *(const short8*)(kB + (size_t)(kw2 + 16 + col) * 8 + quad * 8);
        vfa0 = *(const short8*)(vB + ((size_t)(0 * 16 + col)) * PP + kw2 + quad * 8);
        vfa1 = *(const short8*)(vB + ((size_t)(1 * 16 + col)) * PP + kw2 + quad * 8);
        vfa2 = *(const short8*)(vB + ((size_t)(2 * 16 + col)) * PP + kw2 + quad * 8);
        vfa3 = *(const short8*)(vB + ((size_t)(3 * 16 + col)) * PP + kw2 + quad * 8);

        COMPUTE_TILE(kfb0, kfb1, vfb0, vfb1, vfb2, vfb3)
    }

    // ---- balanced epilogue: wave w owns channels [w*32, w*32+32) ----
    {
        const int ecb0 = (wid == 0) ? 2 : 0;   // export the OTHER half
#pragma unroll
        for (int qh = 0; qh < 4; ++qh)
#pragma unroll
            for (int cbo = 0; cbo < 2; ++cbo)
#pragma unroll
                for (int r = 0; r < 4; ++r)
                    sx[wid][cbo * 16 + quad * 4 + r][qh * 16 + col] = acc[qh][ecb0 + cbo][r];
        if (wid == 1 && quad == 0)
#pragma unroll
            for (int qh = 0; qh < 4; ++qh)
                slsum[qh * 16 + col] = accLh[qh][0];
    }
    __syncthreads();
    {
        const int ocb0 = (wid == 0) ? 0 : 2;   // own half
        ushort* ab = accp + ((size_t)g * BB + b) * CC * PP;
#pragma unroll
        for (int qh = 0; qh < 4; ++qh)
#pragma unroll
            for (int cbo = 0; cbo < 2; ++cbo)
#pragma unroll
                for (int r = 0; r < 4; ++r) {
                    const int cloc = cbo * 16 + quad * 4 + r;
                    const int c = (ocb0 + cbo) * 16 + quad * 4 + r;
                    const float v = acc[qh][ocb0 + cbo][r] + sx[1 - wid][cloc][qh * 16 + col];
                    ab[(size_t)c * PP + q0 + qh * 16 + col] = f2bf(v);
                }
        if (wid == 0 && quad == 0) {
            float* lb = lsump + ((size_t)g * BB + b) * PP + q0;
#pragma unroll
            for (int qh = 0; qh < 4; ++qh)
                lb[qh * 16 + col] = accLh[qh][0] + slsum[qh * 16 + col];
        }
    }
}

// ---------------------------------------------------------------------------
// Kernel 3: combine G partials, normalize, + gamma*attn + x. 576 x 256,
// 8 consecutive pixels per thread (layouts already [b][c][p]-major).
// ---------------------------------------------------------------------------
__global__ __launch_bounds__(256)
void combine(const ushort* __restrict__ accp, const float* __restrict__ lsump,
             const float* __restrict__ x, const float* __restrict__ gamma,
             float* __restrict__ out, int G)
{
    const size_t i8 = ((size_t)blockIdx.x * 256 + threadIdx.x) * 8;
    const int b = (int)(i8 / ((size_t)CC * PP));
    const int p = (int)(i8 % PP);
    const float gm = gamma[0];

    float asum[8] = {}, lst[8] = {};
    for (int g = 0; g < G; ++g) {
        const uint4 av = *(const uint4*)(accp + (size_t)g * (BB * CC * PP) + i8);
        const unsigned int u[4] = {av.x, av.y, av.z, av.w};
#pragma unroll
        for (int k = 0; k < 4; ++k) {
            asum[2 * k]     += __uint_as_float(u[k] << 16);
            asum[2 * k + 1] += __uint_as_float(u[k] & 0xffff0000u);
        }
        const float* lp = lsump + ((size_t)g * BB + b) * PP + p;
        const float4 l0 = *(const float4*)lp;
        const float4 l1 = *(const float4*)(lp + 4);
        lst[0] += l0.x; lst[1] += l0.y; lst[2] += l0.z; lst[3] += l0.w;
        lst[4] += l1.x; lst[5] += l1.y; lst[6] += l1.z; lst[7] += l1.w;
    }

    const float4 x0 = *(const float4*)(x + i8);
    const float4 x1 = *(const float4*)(x + i8 + 4);
    float o[8] = {x0.x, x0.y, x0.z, x0.w, x1.x, x1.y, x1.z, x1.w};
#pragma unroll
    for (int j = 0; j < 8; ++j)
        o[j] = fmaf(asum[j], gm / fmaxf(lst[j], 1e-30f), o[j]);
    *(float4*)(out + i8)     = make_float4(o[0], o[1], o[2], o[3]);
    *(float4*)(out + i8 + 4) = make_float4(o[4], o[5], o[6], o[7]);
}

// ---------------------------------------------------------------------------
extern "C" void kernel_launch(void* const* d_in, const int* in_sizes, int n_in,
                              void* d_out, int out_size, void* d_ws, size_t ws_size,
                              hipStream_t stream)
{
    const float* x     = (const float*)d_in[0];
    const float* Wq    = (const float*)d_in[1];
    const float* bq    = (const float*)d_in[2];
    const float* Wk    = (const float*)d_in[3];
    const float* bk    = (const float*)d_in[4];
    const float* Wv    = (const float*)d_in[5];
    const float* bv    = (const float*)d_in[6];
    const float* gamma = (const float*)d_in[7];
    float* out = (float*)d_out;

    // ws: qbuf | kbuf | vfw (bf16) | accp (bf16, G slots) | lsump (f32)
    const size_t nQK  = (size_t)BB * PP * 8;        // elems
    const size_t nV   = (size_t)BB * CC * PP;
    const size_t base = 2 * nQK * 2 + nV * 2;       // bytes
    const size_t perG = nV * 2 + (size_t)BB * PP * 4;
    const int G = (ws_size >= base + 8 * perG) ? 8
                : (ws_size >= base + 6 * perG) ? 6
                : (ws_size >= base + 4 * perG) ? 4 : 2;
    const int keysPerG = PP / G;
    const int numTiles = keysPerG / 64;             // even for all G above

    ushort* qbuf = (ushort*)d_ws;
    ushort* kbuf = qbuf + nQK;
    ushort* vfw  = kbuf + nQK;
    ushort* accp = vfw + nV;
    float* lsump = (float*)(accp + (size_t)G * nV);

    proj3<<<dim3(BB * 2 * QTILES), dim3(256), 0, stream>>>(
        x, Wq, bq, Wk, bk, Wv, bv, qbuf, kbuf, vfw);
    attn9<<<dim3(G * BB * QTILES), dim3(128), 0, stream>>>(
        qbuf, kbuf, vfw, accp, lsump, keysPerG, numTiles);
    combine<<<dim3(576), dim3(256), 0, stream>>>(
        accp, lsump, x, gamma, out, G);
}

// Round 16
// 142.850 us; speedup vs baseline: 1.1592x; 1.1592x over previous
//
#include <hip/hip_runtime.h>
#include <hip/hip_bf16.h>
#include <stdint.h>

// B,C,H,W = 2,64,96,96. Inputs fp32, output fp32.
// proj3: QKV 1x1 convs -> bf16 q(*log2e), k, V key-PERMUTED channel-major.
// attn10: zero-LDS-loop flash attention, 64q/wave, ping-pong K+V prefetch,
//         Schraudolph bf16 P, ones-row-MFMA denominator. Balanced epilogue
//         with COMPILE-TIME-CONSTANT acc indices (r14/r15's runtime-indexed
//         acc[ecb0+cbo] forced a 256 B/thread accumulator spill: WRITE
//         19->166MB). Every acc[][] index below is a literal.
// combine: sum G key-split partials, normalize, + gamma*attn + x.
#define BB 2
#define CC 64
#define PP 9216
#define QTILES 144               // PP/64
#define LOG2E 1.4426950408889634f
// Schraudolph magic for bf16 2^E bits: E*128 + (127 - 0.05730496)*128
#define SCH_C 16248.664965f

typedef unsigned short ushort;
typedef __attribute__((ext_vector_type(8))) short short8;
typedef __attribute__((ext_vector_type(4))) float floatx4;
typedef __attribute__((ext_vector_type(4))) int intx4;

__device__ __forceinline__ ushort f2bf(float f) {
    unsigned int u = __float_as_uint(f);
    u = (u + 0x7fffu + ((u >> 16) & 1u)) >> 16;   // RNE
    return (ushort)u;
}

// 2^e0, 2^e1 as packed bf16 pair via Schraudolph (arg always > 0 -> trunc=floor)
__device__ __forceinline__ unsigned int exp2_pk_bf16(float e0, float e1) {
    const int i0 = (int)fmaf(e0, 128.f, SCH_C);
    const int i1 = (int)fmaf(e1, 128.f, SCH_C);
    return (unsigned int)i0 | ((unsigned int)i1 << 16);
}

// ---------------------------------------------------------------------------
// Kernel 1: QKV projection. 576 blocks x 256 (4 waves; wave = 64 px x 10 rows;
// 2 blocks per 64-px tile, each covering 40 of the 80 output rows).
// Rows 0-7: q (scaled by LOG2E), 8-15: k, 16-79: v.
// V keys permuted within 32-groups: slot = ((k>>2)&3)*8 + ((k>>4)&1)*4 + (k&3)
// so PV's B-operand slot k'=quad*8+j matches QK's D[key][q] output rows.
// ---------------------------------------------------------------------------
__global__ __launch_bounds__(256)
void proj3(const float* __restrict__ x,
           const float* __restrict__ Wq, const float* __restrict__ bq,
           const float* __restrict__ Wk, const float* __restrict__ bk,
           const float* __restrict__ Wv, const float* __restrict__ bv,
           ushort* __restrict__ qbuf, ushort* __restrict__ kbuf,
           ushort* __restrict__ vfw)
{
    const int tid = threadIdx.x;
    const int px  = tid & 63;
    const int og  = __builtin_amdgcn_readfirstlane(tid >> 6);  // 0..3, wave-uniform
    const int blk = blockIdx.x;
    const int b     = blk / (2 * QTILES);
    const int rem   = blk % (2 * QTILES);
    const int ptile = rem >> 1;
    const int rhalf = rem & 1;
    const int p     = ptile * 64 + px;
    const int r0    = rhalf * 40 + og * 10;      // first of this thread's 10 rows

    const float* wr[10];
#pragma unroll
    for (int r = 0; r < 10; ++r) {
        const int row = r0 + r;
        wr[r] = (row < 8) ? (Wq + row * 64)
              : (row < 16) ? (Wk + (row - 8) * 64)
              : (Wv + (row - 16) * 64);
    }

    float xv[64];
#pragma unroll
    for (int c = 0; c < 64; ++c)
        xv[c] = x[((size_t)b * 64 + c) * PP + p];

    float acc[10];
#pragma unroll
    for (int r = 0; r < 10; ++r) acc[r] = 0.f;
#pragma unroll
    for (int c = 0; c < 64; ++c) {
#pragma unroll
        for (int r = 0; r < 10; ++r)
            acc[r] = fmaf(wr[r][c], xv[c], acc[r]);
    }

#pragma unroll
    for (int r = 0; r < 10; ++r) {
        const int row = r0 + r;
        if (row < 8) {
            const float v = (acc[r] + bq[row]) * LOG2E;
            qbuf[((size_t)b * PP + p) * 8 + row] = f2bf(v);
        } else if (row < 16) {
            const float v = acc[r] + bk[row - 8];
            kbuf[((size_t)b * PP + p) * 8 + (row - 8)] = f2bf(v);
        } else {
            const int co = row - 16;
            const float v = acc[r] + bv[co];
            const int pl = p & 31;     // slot permutation within 32-group
            const int ps = (p & ~31) | ((((pl >> 2) & 3) << 3) | (((pl >> 4) & 1) << 2) | (pl & 3));
            vfw[((size_t)b * 64 + co) * PP + ps] = f2bf(v);
        }
    }
}

// One tile's compute: QK (A=K, B=Q) -> Schraudolph bf16 P -> lsum MFMA -> PV.
// All register indices compile-time constants.
#define COMPUTE_TILE(K0, K1, V0, V1, V2, V3)                                   \
    _Pragma("unroll")                                                          \
    for (int qh = 0; qh < 4; ++qh) {                                           \
        const floatx4 E0 = __builtin_amdgcn_mfma_f32_16x16x32_bf16(            \
            K0, qfragB[qh], (floatx4){0.f, 0.f, 0.f, 0.f}, 0, 0, 0);           \
        const floatx4 E1 = __builtin_amdgcn_mfma_f32_16x16x32_bf16(            \
            K1, qfragB[qh], (floatx4){0.f, 0.f, 0.f, 0.f}, 0, 0, 0);           \
        intx4 pi;                                                              \
        pi.x = (int)exp2_pk_bf16(E0[0], E0[1]);                                \
        pi.y = (int)exp2_pk_bf16(E0[2], E0[3]);                                \
        pi.z = (int)exp2_pk_bf16(E1[0], E1[1]);                                \
        pi.w = (int)exp2_pk_bf16(E1[2], E1[3]);                                \
        const short8 pf = __builtin_bit_cast(short8, pi);                      \
        accLh[qh] = __builtin_amdgcn_mfma_f32_16x16x32_bf16(                   \
            vones, pf, accLh[qh], 0, 0, 0);                                    \
        acc[qh][0] = __builtin_amdgcn_mfma_f32_16x16x32_bf16(                  \
            V0, pf, acc[qh][0], 0, 0, 0);                                      \
        acc[qh][1] = __builtin_amdgcn_mfma_f32_16x16x32_bf16(                  \
            V1, pf, acc[qh][1], 0, 0, 0);                                      \
        acc[qh][2] = __builtin_amdgcn_mfma_f32_16x16x32_bf16(                  \
            V2, pf, acc[qh][2], 0, 0, 0);                                      \
        acc[qh][3] = __builtin_amdgcn_mfma_f32_16x16x32_bf16(                  \
            V3, pf, acc[qh][3], 0, 0, 0);                                      \
    }

// ---------------------------------------------------------------------------
// Kernel 2: zero-LDS-loop MFMA flash attention, 64q/wave, ping-pong K+V
// prefetch. Grid = G*BB*QTILES blocks of 128 (2 waves; wave = 64 q x 32 keys
// of each 64-key tile). K quads 1-3 load garbage (Q k-slots >=8 zeroed ->
// contributes exactly 0). V key-permuted to PV slot order.
// ---------------------------------------------------------------------------
__global__ __launch_bounds__(128, 3)
void attn10(const ushort* __restrict__ qbuf, const ushort* __restrict__ kbuf,
            const ushort* __restrict__ vfw,
            ushort* __restrict__ accp, float* __restrict__ lsump,
            int keysPerG, int numTiles)
{
    __shared__ __align__(16) float sx[2][32][66];  // padded: quad-stride 264 % 32 = 8
    __shared__ float slsum[64];

    const int tid  = threadIdx.x;
    const int lane = tid & 63;
    const int wid  = tid >> 6;
    const int col  = lane & 15;
    const int quad = lane >> 4;

    const int qt = blockIdx.x % QTILES;
    const int gb = blockIdx.x / QTILES;
    const int b  = gb % BB;
    const int g  = gb / BB;
    const int q0 = qt * 64;

    const short8 zf = {0, 0, 0, 0, 0, 0, 0, 0};
    const short vone = (short)0x3F80;                 // bf16 1.0
    const short8 vones = {vone, vone, vone, vone, vone, vone, vone, vone};

    // Q fragments (B-operand: B[k=d=quad*8+j][n=q=col]); only quad 0 real.
    short8 qfragB[4];
#pragma unroll
    for (int qh = 0; qh < 4; ++qh)
        qfragB[qh] = (quad == 0)
            ? *(const short8*)(qbuf + ((size_t)b * PP + q0 + qh * 16 + col) * 8)
            : zf;

    floatx4 acc[4][4];
#pragma unroll
    for (int qh = 0; qh < 4; ++qh)
#pragma unroll
        for (int cb = 0; cb < 4; ++cb) acc[qh][cb] = (floatx4){0.f, 0.f, 0.f, 0.f};
    floatx4 accLh[4];
#pragma unroll
    for (int qh = 0; qh < 4; ++qh) accLh[qh] = (floatx4){0.f, 0.f, 0.f, 0.f};

    const ushort* kB = kbuf + (size_t)b * PP * 8;
    const ushort* vB = vfw + (size_t)b * 64 * PP;
    const int kwbase = g * keysPerG + wid * 32;

    // ---- prologue: tile 0 into A-buffers ----
    short8 kfa0 = *(const short8*)(kB + (size_t)(kwbase + col) * 8 + quad * 8);
    short8 kfa1 = *(const short8*)(kB + (size_t)(kwbase + 16 + col) * 8 + quad * 8);
    short8 vfa0 = *(const short8*)(vB + ((size_t)(0 * 16 + col)) * PP + kwbase + quad * 8);
    short8 vfa1 = *(const short8*)(vB + ((size_t)(1 * 16 + col)) * PP + kwbase + quad * 8);
    short8 vfa2 = *(const short8*)(vB + ((size_t)(2 * 16 + col)) * PP + kwbase + quad * 8);
    short8 vfa3 = *(const short8*)(vB + ((size_t)(3 * 16 + col)) * PP + kwbase + quad * 8);

    // numTiles is even for every G in the ladder (18/24/36/72)
    for (int t = 0; t < numTiles; t += 2) {
        // -- half A: prefetch tile t+1 into B-buffers, compute tile t --
        const int kw1 = kwbase + (t + 1) * 64;
        const short8 kfb0 = *(const short8*)(kB + (size_t)(kw1 + col) * 8 + quad * 8);
        const short8 kfb1 = *(const short8*)(kB + (size_t)(kw1 + 16 + col) * 8 + quad * 8);
        const short8 vfb0 = *(const short8*)(vB + ((size_t)(0 * 16 + col)) * PP + kw1 + quad * 8);
        const short8 vfb1 = *(const short8*)(vB + ((size_t)(1 * 16 + col)) * PP + kw1 + quad * 8);
        const short8 vfb2 = *(const short8*)(vB + ((size_t)(2 * 16 + col)) * PP + kw1 + quad * 8);
        const short8 vfb3 = *(const short8*)(vB + ((size_t)(3 * 16 + col)) * PP + kw1 + quad * 8);

        COMPUTE_TILE(kfa0, kfa1, vfa0, vfa1, vfa2, vfa3)

        // -- half B: prefetch tile t+2 into A-buffers, compute tile t+1 --
        const int kw2 = (t + 2 < numTiles) ? (kwbase + (t + 2) * 64) : kw1;
        kfa0 = *(const short8*)(kB + (size_t)(kw2 + col) * 8 + quad * 8);
        kfa1 = *(const short8*)(kB + (size_t)(kw2 + 16 + col) * 8 + quad * 8);
        vfa0 = *(const short8*)(vB + ((size_t)(0 * 16 + col)) * PP + kw2 + quad * 8);
        vfa1 = *(const short8*)(vB + ((size_t)(1 * 16 + col)) * PP + kw2 + quad * 8);
        vfa2 = *(const short8*)(vB + ((size_t)(2 * 16 + col)) * PP + kw2 + quad * 8);
        vfa3 = *(const short8*)(vB + ((size_t)(3 * 16 + col)) * PP + kw2 + quad * 8);

        COMPUTE_TILE(kfb0, kfb1, vfb0, vfb1, vfb2, vfb3)
    }

    // ---- balanced epilogue, ALL acc indices literal ----
    // wave 0 owns ch0-31 (acc[.][0],[1]), exports ch32-63 ([2],[3]);
    // wave 1 owns ch32-63, exports ch0-31.
    if (wid == 0) {
#pragma unroll
        for (int qh = 0; qh < 4; ++qh)
#pragma unroll
            for (int r = 0; r < 4; ++r) {
                sx[0][0 * 16 + quad * 4 + r][qh * 16 + col] = acc[qh][2][r];
                sx[0][1 * 16 + quad * 4 + r][qh * 16 + col] = acc[qh][3][r];
            }
    } else {
#pragma unroll
        for (int qh = 0; qh < 4; ++qh)
#pragma unroll
            for (int r = 0; r < 4; ++r) {
                sx[1][0 * 16 + quad * 4 + r][qh * 16 + col] = acc[qh][0][r];
                sx[1][1 * 16 + quad * 4 + r][qh * 16 + col] = acc[qh][1][r];
            }
        if (quad == 0)
#pragma unroll
            for (int qh = 0; qh < 4; ++qh)
                slsum[qh * 16 + col] = accLh[qh][0];
    }
    __syncthreads();
    {
        ushort* ab = accp + ((size_t)g * BB + b) * CC * PP;
        if (wid == 0) {
#pragma unroll
            for (int qh = 0; qh < 4; ++qh)
#pragma unroll
                for (int r = 0; r < 4; ++r) {
                    const int c0 = 0 * 16 + quad * 4 + r;
                    const int c1 = 1 * 16 + quad * 4 + r;
                    const float v0 = acc[qh][0][r] + sx[1][c0][qh * 16 + col];
                    const float v1 = acc[qh][1][r] + sx[1][c1][qh * 16 + col];
                    ab[(size_t)c0 * PP + q0 + qh * 16 + col] = f2bf(v0);
                    ab[(size_t)c1 * PP + q0 + qh * 16 + col] = f2bf(v1);
                }
            if (quad == 0) {
                float* lb = lsump + ((size_t)g * BB + b) * PP + q0;
#pragma unroll
                for (int qh = 0; qh < 4; ++qh)
                    lb[qh * 16 + col] = accLh[qh][0] + slsum[qh * 16 + col];
            }
        } else {
#pragma unroll
            for (int qh = 0; qh < 4; ++qh)
#pragma unroll
                for (int r = 0; r < 4; ++r) {
                    const int l0 = 0 * 16 + quad * 4 + r;
                    const int l1 = 1 * 16 + quad * 4 + r;
                    const float v0 = acc[qh][2][r] + sx[0][l0][qh * 16 + col];
                    const float v1 = acc[qh][3][r] + sx[0][l1][qh * 16 + col];
                    ab[(size_t)(32 + l0) * PP + q0 + qh * 16 + col] = f2bf(v0);
                    ab[(size_t)(32 + l1) * PP + q0 + qh * 16 + col] = f2bf(v1);
                }
        }
    }
}

// ---------------------------------------------------------------------------
// Kernel 3: combine G partials, normalize, + gamma*attn + x. 576 x 256,
// 8 consecutive pixels per thread (layouts already [b][c][p]-major).
// ---------------------------------------------------------------------------
__global__ __launch_bounds__(256)
void combine(const ushort* __restrict__ accp, const float* __restrict__ lsump,
             const float* __restrict__ x, const float* __restrict__ gamma,
             float* __restrict__ out, int G)
{
    const size_t i8 = ((size_t)blockIdx.x * 256 + threadIdx.x) * 8;
    const int b = (int)(i8 / ((size_t)CC * PP));
    const int p = (int)(i8 % PP);
    const float gm = gamma[0];

    float asum[8] = {}, lst[8] = {};
    for (int g = 0; g < G; ++g) {
        const uint4 av = *(const uint4*)(accp + (size_t)g * (BB * CC * PP) + i8);
        const unsigned int u[4] = {av.x, av.y, av.z, av.w};
#pragma unroll
        for (int k = 0; k < 4; ++k) {
            asum[2 * k]     += __uint_as_float(u[k] << 16);
            asum[2 * k + 1] += __uint_as_float(u[k] & 0xffff0000u);
        }
        const float* lp = lsump + ((size_t)g * BB + b) * PP + p;
        const float4 l0 = *(const float4*)lp;
        const float4 l1 = *(const float4*)(lp + 4);
        lst[0] += l0.x; lst[1] += l0.y; lst[2] += l0.z; lst[3] += l0.w;
        lst[4] += l1.x; lst[5] += l1.y; lst[6] += l1.z; lst[7] += l1.w;
    }

    const float4 x0 = *(const float4*)(x + i8);
    const float4 x1 = *(const float4*)(x + i8 + 4);
    float o[8] = {x0.x, x0.y, x0.z, x0.w, x1.x, x1.y, x1.z, x1.w};
#pragma unroll
    for (int j = 0; j < 8; ++j)
        o[j] = fmaf(asum[j], gm / fmaxf(lst[j], 1e-30f), o[j]);
    *(float4*)(out + i8)     = make_float4(o[0], o[1], o[2], o[3]);
    *(float4*)(out + i8 + 4) = make_float4(o[4], o[5], o[6], o[7]);
}

// ---------------------------------------------------------------------------
extern "C" void kernel_launch(void* const* d_in, const int* in_sizes, int n_in,
                              void* d_out, int out_size, void* d_ws, size_t ws_size,
                              hipStream_t stream)
{
    const float* x     = (const float*)d_in[0];
    const float* Wq    = (const float*)d_in[1];
    const float* bq    = (const float*)d_in[2];
    const float* Wk    = (const float*)d_in[3];
    const float* bk    = (const float*)d_in[4];
    const float* Wv    = (const float*)d_in[5];
    const float* bv    = (const float*)d_in[6];
    const float* gamma = (const float*)d_in[7];
    float* out = (float*)d_out;

    // ws: qbuf | kbuf | vfw (bf16) | accp (bf16, G slots) | lsump (f32)
    const size_t nQK  = (size_t)BB * PP * 8;        // elems
    const size_t nV   = (size_t)BB * CC * PP;
    const size_t base = 2 * nQK * 2 + nV * 2;       // bytes
    const size_t perG = nV * 2 + (size_t)BB * PP * 4;
    const int G = (ws_size >= base + 8 * perG) ? 8
                : (ws_size >= base + 6 * perG) ? 6
                : (ws_size >= base + 4 * perG) ? 4 : 2;
    const int keysPerG = PP / G;
    const int numTiles = keysPerG / 64;             // even for all G above

    ushort* qbuf = (ushort*)d_ws;
    ushort* kbuf = qbuf + nQK;
    ushort* vfw  = kbuf + nQK;
    ushort* accp = vfw + nV;
    float* lsump = (float*)(accp + (size_t)G * nV);

    proj3<<<dim3(BB * 2 * QTILES), dim3(256), 0, stream>>>(
        x, Wq, bq, Wk, bk, Wv, bv, qbuf, kbuf, vfw);
    attn10<<<dim3(G * BB * QTILES), dim3(128), 0, stream>>>(
        qbuf, kbuf, vfw, accp, lsump, keysPerG, numTiles);
    combine<<<dim3(576), dim3(256), 0, stream>>>(
        accp, lsump, x, gamma, out, G);
}